// Round 1
// baseline (494.729 us; speedup 1.0000x reference)
//
#include <hip/hip_runtime.h>

#define M_DIM 4096
#define K_DIM 4096
#define N_DIM 11008
#define PQ (N_DIM / 8)   // 1376 packed columns
#define GQ 32            // K/128 groups

typedef short short8 __attribute__((ext_vector_type(8)));
typedef float f32x4 __attribute__((ext_vector_type(4)));
typedef __attribute__((address_space(3))) void lds_void;
typedef const __attribute__((address_space(1))) void g_void;

__device__ __forceinline__ unsigned short f2bf(float f) {
  unsigned int u = __float_as_uint(f);
  u += 0x7FFFu + ((u >> 16) & 1u);   // round-to-nearest-even
  return (unsigned short)(u >> 16);
}

// ---------------- A conversion: fp32 [M][K] -> bf16 [M][K] ----------------
__global__ __launch_bounds__(256) void convert_a(const float* __restrict__ a,
                                                 unsigned short* __restrict__ ab) {
  size_t idx = (size_t)blockIdx.x * 256 + threadIdx.x;  // one per 8 floats
  const float4* src = (const float4*)a + idx * 2;
  float4 v0 = src[0];
  float4 v1 = src[1];
  short8 o;
  o[0] = (short)f2bf(v0.x); o[1] = (short)f2bf(v0.y);
  o[2] = (short)f2bf(v0.z); o[3] = (short)f2bf(v0.w);
  o[4] = (short)f2bf(v1.x); o[5] = (short)f2bf(v1.y);
  o[6] = (short)f2bf(v1.z); o[7] = (short)f2bf(v1.w);
  *(short8*)(ab + idx * 8) = o;
}

// ------------- Dequant: qweight [K][P] int32 -> Wg [K/8][N][8] bf16 -------------
// Wg[kb][n][e] = W[kb*8+e][n]; thread per (kb, n) -> one contiguous 16B store.
__global__ __launch_bounds__(256) void dequant_w(const int* __restrict__ qweight,
                                                 const int* __restrict__ qzeros,
                                                 const float* __restrict__ scales,
                                                 unsigned short* __restrict__ wg) {
  int idx = blockIdx.x * 256 + threadIdx.x;
  int n = idx % N_DIM;
  int kb = idx / N_DIM;                 // 0..511
  int g = kb >> 4;                      // kb*8/128
  int p = n >> 3;
  int j = n & 7;
  // AWQ reverse order [0,4,1,5,2,6,3,7]: shift = 4*rev[j]
  int sh = ((j >> 1) << 2) | ((j & 1) << 4);
  float zp = (float)((qzeros[g * PQ + p] >> sh) & 0xF);
  float sc = scales[(size_t)g * N_DIM + n];
  short8 o;
#pragma unroll
  for (int e = 0; e < 8; ++e) {
    int q = qweight[(size_t)(kb * 8 + e) * PQ + p];
    float w = ((float)((q >> sh) & 0xF) - zp) * sc;
    o[e] = (short)f2bf(w);
  }
  *(short8*)(wg + ((size_t)kb * N_DIM + n) * 8) = o;
}

// ---------------- bf16 MFMA GEMM: C = A @ W + bias ----------------
// 128x128 tile, BK=64, 256 threads (4 waves, 2x2), 4x4 16x16x32 fragments/wave.
#define BM 128
#define BN 128
#define BK 64

__global__ __launch_bounds__(256) void gemm_bf16(const unsigned short* __restrict__ A,
                                                 const unsigned short* __restrict__ B,
                                                 const float* __restrict__ bias,
                                                 float* __restrict__ C) {
  __shared__ unsigned short lds_a[BM * BK];            // 16 KB, XOR-swizzled rows
  __shared__ unsigned short lds_b[(BK / 8) * BN * 8];  // 16 KB, [kbl][n][e]

  const int tid = threadIdx.x;
  const int lane = tid & 63;
  const int wave = tid >> 6;
  const int wr = wave >> 1, wc = wave & 1;
  const int tm = blockIdx.x & 31;   // 32 M-tiles (fast) -> same-tn blocks adjacent
  const int tn = blockIdx.x >> 5;   // 86 N-tiles
  const int m0 = tm * BM, n0 = tn * BN;

  f32x4 zero = {0.f, 0.f, 0.f, 0.f};
  f32x4 acc[4][4];
#pragma unroll
  for (int i = 0; i < 4; ++i)
#pragma unroll
    for (int jj = 0; jj < 4; ++jj) acc[i][jj] = zero;

  for (int k0 = 0; k0 < K_DIM; k0 += BK) {
    // ---- stage A tile: rows swizzled (slot ^= row&7) via pre-swizzled global src
#pragma unroll
    for (int i = 0; i < 4; ++i) {
      int c = i * 256 + tid;          // 16B-chunk id, 8 chunks per row
      int r = c >> 3;
      int scr = (c & 7) ^ (r & 7);    // source slot within the 128B row
      const unsigned short* src = A + (size_t)(m0 + r) * K_DIM + k0 + scr * 8;
      __builtin_amdgcn_global_load_lds((g_void*)src,
          (lds_void*)(lds_a + (size_t)(i * 256 + wave * 64) * 8), 16, 0, 0);
    }
    // ---- stage B tile: linear, already K-packed in global
#pragma unroll
    for (int i = 0; i < 4; ++i) {
      int c = i * 256 + tid;
      int kbl = c >> 7;               // 0..7
      int jn = c & 127;               // n offset
      const unsigned short* src = B + ((size_t)((k0 >> 3) + kbl) * N_DIM + n0 + jn) * 8;
      __builtin_amdgcn_global_load_lds((g_void*)src,
          (lds_void*)(lds_b + (size_t)(i * 256 + wave * 64) * 8), 16, 0, 0);
    }
    __syncthreads();  // drains vmcnt

#pragma unroll
    for (int kk = 0; kk < 2; ++kk) {
      short8 af[4], bf[4];
#pragma unroll
      for (int mi = 0; mi < 4; ++mi) {
        int r = wr * 64 + mi * 16 + (lane & 15);
        int slot = kk * 4 + (lane >> 4);
        int off = r * 128 + (((slot ^ (r & 7)) << 4));  // bytes
        af[mi] = *(const short8*)((const char*)lds_a + off);
      }
#pragma unroll
      for (int ni = 0; ni < 4; ++ni) {
        int off = ((kk * 4 + (lane >> 4)) * BN + wc * 64 + ni * 16 + (lane & 15)) * 16;  // bytes
        bf[ni] = *(const short8*)((const char*)lds_b + off);
      }
#pragma unroll
      for (int mi = 0; mi < 4; ++mi)
#pragma unroll
        for (int ni = 0; ni < 4; ++ni)
          acc[mi][ni] = __builtin_amdgcn_mfma_f32_16x16x32_bf16(af[mi], bf[ni], acc[mi][ni], 0, 0, 0);
    }
    __syncthreads();
  }

  // ---- epilogue: D col = lane&15, row = (lane>>4)*4 + reg
  const int col0 = n0 + wc * 64 + (lane & 15);
  const int row0 = m0 + wr * 64 + ((lane >> 4) << 2);
#pragma unroll
  for (int ni = 0; ni < 4; ++ni) {
    float bv = bias[col0 + ni * 16];
#pragma unroll
    for (int mi = 0; mi < 4; ++mi) {
#pragma unroll
      for (int rr = 0; rr < 4; ++rr) {
        C[(size_t)(row0 + mi * 16 + rr) * N_DIM + col0 + ni * 16] = acc[mi][ni][rr] + bv;
      }
    }
  }
}

// ---------------- fallback: fused-dequant fp32 tiled GEMM (no workspace) ----------------
__global__ __launch_bounds__(256) void gemm_fb(const float* __restrict__ A,
                                               const int* __restrict__ qweight,
                                               const int* __restrict__ qzeros,
                                               const float* __restrict__ scales,
                                               const float* __restrict__ bias,
                                               float* __restrict__ C) {
  __shared__ float as[64][17];
  __shared__ float bs[16][65];
  int tid = threadIdx.x;
  int tx = tid & 15, ty = tid >> 4;
  int bn = blockIdx.x % (N_DIM / 64);
  int bm = blockIdx.x / (N_DIM / 64);
  int m0 = bm * 64, n0 = bn * 64;
  float acc[4][4] = {};
  for (int k0 = 0; k0 < K_DIM; k0 += 16) {
#pragma unroll
    for (int i = 0; i < 4; ++i) {
      int idx = i * 256 + tid;
      int r = idx >> 4, c = idx & 15;
      as[r][c] = A[(size_t)(m0 + r) * K_DIM + k0 + c];
    }
#pragma unroll
    for (int i = 0; i < 4; ++i) {
      int idx = i * 256 + tid;
      int r = idx >> 6, c = idx & 63;
      int k = k0 + r, n = n0 + c;
      int g = k >> 7, p = n >> 3, j = n & 7;
      int sh = ((j >> 1) << 2) | ((j & 1) << 4);
      int q = qweight[(size_t)k * PQ + p];
      int zq = qzeros[(size_t)g * PQ + p];
      bs[r][c] = (float)(((q >> sh) & 0xF) - ((zq >> sh) & 0xF)) * scales[(size_t)g * N_DIM + n];
    }
    __syncthreads();
#pragma unroll
    for (int kk = 0; kk < 16; ++kk) {
      float av[4], bv[4];
#pragma unroll
      for (int i = 0; i < 4; ++i) av[i] = as[ty * 4 + i][kk];
#pragma unroll
      for (int i = 0; i < 4; ++i) bv[i] = bs[kk][tx * 4 + i];
#pragma unroll
      for (int i = 0; i < 4; ++i)
#pragma unroll
        for (int j2 = 0; j2 < 4; ++j2) acc[i][j2] += av[i] * bv[j2];
    }
    __syncthreads();
  }
#pragma unroll
  for (int i = 0; i < 4; ++i)
#pragma unroll
    for (int j2 = 0; j2 < 4; ++j2)
      C[(size_t)(m0 + ty * 4 + i) * N_DIM + n0 + tx * 4 + j2] =
          acc[i][j2] + bias[n0 + tx * 4 + j2];
}

extern "C" void kernel_launch(void* const* d_in, const int* in_sizes, int n_in,
                              void* d_out, int out_size, void* d_ws, size_t ws_size,
                              hipStream_t stream) {
  const float* inputs = (const float*)d_in[0];
  const int* qweight = (const int*)d_in[1];
  const int* qzeros = (const int*)d_in[2];
  const float* scales = (const float*)d_in[3];
  const float* bias = (const float*)d_in[4];
  float* out = (float*)d_out;

  const size_t a_bytes = (size_t)M_DIM * K_DIM * 2;  // 32 MB
  const size_t w_bytes = (size_t)K_DIM * N_DIM * 2;  // 86 MB

  if (ws_size >= a_bytes + w_bytes) {
    unsigned short* a_bf = (unsigned short*)d_ws;
    unsigned short* wg = (unsigned short*)((char*)d_ws + a_bytes);
    convert_a<<<(M_DIM * K_DIM / 8) / 256, 256, 0, stream>>>(inputs, a_bf);
    dequant_w<<<((K_DIM / 8) * N_DIM) / 256, 256, 0, stream>>>(qweight, qzeros, scales, wg);
    gemm_bf16<<<(M_DIM / BM) * (N_DIM / BN), 256, 0, stream>>>(a_bf, wg, bias, out);
  } else {
    gemm_fb<<<(M_DIM / 64) * (N_DIM / 64), 256, 0, stream>>>(inputs, qweight, qzeros, scales,
                                                             bias, out);
  }
}

// Round 2
// 397.013 us; speedup vs baseline: 1.2461x; 1.2461x over previous
//
#include <hip/hip_runtime.h>

#define M_DIM 4096
#define K_DIM 4096
#define N_DIM 11008
#define PQ (N_DIM / 8)   // 1376 packed columns

typedef short short8 __attribute__((ext_vector_type(8)));
typedef float f32x4 __attribute__((ext_vector_type(4)));
typedef __attribute__((address_space(3))) void lds_void;
typedef const __attribute__((address_space(1))) void g_void;

__device__ __forceinline__ unsigned short f2bf(float f) {
  unsigned int u = __float_as_uint(f);
  u += 0x7FFFu + ((u >> 16) & 1u);   // round-to-nearest-even
  return (unsigned short)(u >> 16);
}

// ---- A convert + transpose: fp32 [M][K] -> bf16 K-packed Ag[K/8][M][8] ----
// Ag[kb][m][e] = A[m][kb*8+e]
__global__ __launch_bounds__(256) void convert_a_t(const float* __restrict__ a,
                                                   unsigned short* __restrict__ ag) {
  int idx = blockIdx.x * 256 + threadIdx.x;   // (kb, m), m fast
  int m = idx & (M_DIM - 1);
  int kb = idx >> 12;
  const float4* src = (const float4*)(a + (size_t)m * K_DIM + kb * 8);
  float4 v0 = src[0];
  float4 v1 = src[1];
  short8 o;
  o[0] = (short)f2bf(v0.x); o[1] = (short)f2bf(v0.y);
  o[2] = (short)f2bf(v0.z); o[3] = (short)f2bf(v0.w);
  o[4] = (short)f2bf(v1.x); o[5] = (short)f2bf(v1.y);
  o[6] = (short)f2bf(v1.z); o[7] = (short)f2bf(v1.w);
  *(short8*)(ag + (size_t)idx * 8) = o;       // coalesced writes
}

// ---- Dequant: qweight [K][P] int32 -> Wg [K/8][N][8] bf16 (K-packed) ----
__global__ __launch_bounds__(256) void dequant_w(const int* __restrict__ qweight,
                                                 const int* __restrict__ qzeros,
                                                 const float* __restrict__ scales,
                                                 unsigned short* __restrict__ wg) {
  int idx = blockIdx.x * 256 + threadIdx.x;
  int n = idx % N_DIM;
  int kb = idx / N_DIM;                 // 0..511
  int g = kb >> 4;                      // kb*8/128
  int p = n >> 3;
  int j = n & 7;
  int sh = ((j >> 1) << 2) | ((j & 1) << 4);   // 4*AWQ_rev[j]
  float zp = (float)((qzeros[g * PQ + p] >> sh) & 0xF);
  float sc = scales[(size_t)g * N_DIM + n];
  short8 o;
#pragma unroll
  for (int e = 0; e < 8; ++e) {
    int q = qweight[(size_t)(kb * 8 + e) * PQ + p];
    float w = ((float)((q >> sh) & 0xF) - zp) * sc;
    o[e] = (short)f2bf(w);
  }
  *(short8*)(wg + ((size_t)kb * N_DIM + n) * 8) = o;
}

// ---------------- 256x256 8-wave 4-phase bf16 MFMA GEMM ----------------
#define BM 256
#define BN 256
#define BK 64
#define NT (K_DIM / BK)   // 64 K-tiles
// LDS: 2 bufs x (A 16384 + B 16384) shorts = 128 KiB
// A buf layout: [kslot 0..7][row 0..255][8]  (shorts off = kslot*2048 + r*8)
// B buf layout: [kslot 0..7][col 0..255][8]  (+16384)

__device__ __forceinline__ void stage_half(const unsigned short* __restrict__ g, int ld, int off0,
                                           int krow0, unsigned short* ldsbase, int tid, int wid) {
#pragma unroll
  for (int i = 0; i < 2; ++i) {
    int c = i * 512 + tid;             // chunk id within the 16KB half
    const unsigned short* src = g + ((size_t)(krow0 + (c >> 8)) * ld + off0 + (c & 255)) * 8;
    unsigned short* dst = ldsbase + (i * 512 + wid * 64) * 8;  // wave-uniform; lane adds 16B
    __builtin_amdgcn_global_load_lds((g_void*)src, (lds_void*)dst, 16, 0, 0);
  }
}

__global__ __launch_bounds__(512, 2) void gemm256(const unsigned short* __restrict__ Ag,
                                                  const unsigned short* __restrict__ Wg,
                                                  const float* __restrict__ bias,
                                                  float* __restrict__ C) {
  extern __shared__ __align__(16) unsigned short lds[];   // 65536 shorts = 128 KB
  const int tid = threadIdx.x;
  const int lane = tid & 63;
  const int wid = tid >> 6;      // 0..7
  const int wr = wid >> 2;       // 0..1  (row half: 128 rows)
  const int wc = wid & 3;        // 0..3  (col quarter: 64 cols)
  // XCD-bijective swizzle: 688 blocks, 688 % 8 == 0
  const int wg = (blockIdx.x & 7) * 86 + (blockIdx.x >> 3);
  const int m0 = (wg & 15) * BM;
  const int n0 = (wg >> 4) * BN;

  const int ks = lane >> 4;           // k-slot within half (0..3)
  const int rowA = wr * 128 + (lane & 15);
  const int colB = wc * 64 + (lane & 15);

  f32x4 acc[8][4];
#pragma unroll
  for (int i = 0; i < 8; ++i)
#pragma unroll
    for (int j = 0; j < 4; ++j) acc[i][j] = (f32x4){0.f, 0.f, 0.f, 0.f};

#define A_FRAG(kb, mi) (*(const short8*)(lds + bs * 32768 + (kb) * 2048 + (rowA + (mi) * 16) * 8))
#define B_FRAG(kb, ni) (*(const short8*)(lds + bs * 32768 + 16384 + (kb) * 2048 + (colB + (ni) * 16) * 8))

  // ---- prologue: stage tile 0 halves (A0,B0,A1,B1), wait for A0,B0 only
  stage_half(Ag, M_DIM, m0, 0, lds + 0, tid, wid);
  stage_half(Wg, N_DIM, n0, 0, lds + 16384, tid, wid);
  stage_half(Ag, M_DIM, m0, 4, lds + 8192, tid, wid);
  stage_half(Wg, N_DIM, n0, 4, lds + 16384 + 8192, tid, wid);
  asm volatile("s_waitcnt vmcnt(4)" ::: "memory");
  __builtin_amdgcn_s_barrier();

  for (int t = 0; t < NT; ++t) {
    const int bs = t & 1;
    const int nb = bs ^ 1;
    const int t1 = (t + 1 < NT) ? (t + 1) : t;     // duplicate-stage last tile (never read)
    unsigned short* nA = lds + nb * 32768;
    unsigned short* nB = nA + 16384;
    short8 aF[4], bF[4];

    // ===== P1: k-half 0, mi 0-3 =====
#pragma unroll
    for (int ni = 0; ni < 4; ++ni) bF[ni] = B_FRAG(ks, ni);
#pragma unroll
    for (int mi = 0; mi < 4; ++mi) aF[mi] = A_FRAG(ks, mi);
    stage_half(Ag, M_DIM, m0, t1 * 8, nA, tid, wid);           // t+1 A-half0
    __builtin_amdgcn_s_barrier();
    __builtin_amdgcn_sched_barrier(0);
    __builtin_amdgcn_s_setprio(1);
#pragma unroll
    for (int mi = 0; mi < 4; ++mi)
#pragma unroll
      for (int ni = 0; ni < 4; ++ni)
        acc[mi][ni] = __builtin_amdgcn_mfma_f32_16x16x32_bf16(aF[mi], bF[ni], acc[mi][ni], 0, 0, 0);
    __builtin_amdgcn_s_setprio(0);
    __builtin_amdgcn_s_barrier();
    __builtin_amdgcn_sched_barrier(0);

    // ===== P2: k-half 0, mi 4-7 =====
#pragma unroll
    for (int mi = 0; mi < 4; ++mi) aF[mi] = A_FRAG(ks, 4 + mi);
    stage_half(Wg, N_DIM, n0, t1 * 8, nB, tid, wid);           // t+1 B-half0
    asm volatile("s_waitcnt vmcnt(4)" ::: "memory");           // drain this tile's A1,B1
    __builtin_amdgcn_s_barrier();
    __builtin_amdgcn_sched_barrier(0);
    __builtin_amdgcn_s_setprio(1);
#pragma unroll
    for (int mi = 0; mi < 4; ++mi)
#pragma unroll
      for (int ni = 0; ni < 4; ++ni)
        acc[4 + mi][ni] = __builtin_amdgcn_mfma_f32_16x16x32_bf16(aF[mi], bF[ni], acc[4 + mi][ni], 0, 0, 0);
    __builtin_amdgcn_s_setprio(0);
    __builtin_amdgcn_s_barrier();
    __builtin_amdgcn_sched_barrier(0);

    // ===== P3: k-half 1, mi 0-3 =====
#pragma unroll
    for (int ni = 0; ni < 4; ++ni) bF[ni] = B_FRAG(4 + ks, ni);
#pragma unroll
    for (int mi = 0; mi < 4; ++mi) aF[mi] = A_FRAG(4 + ks, mi);
    stage_half(Ag, M_DIM, m0, t1 * 8 + 4, nA + 8192, tid, wid); // t+1 A-half1
    __builtin_amdgcn_s_barrier();
    __builtin_amdgcn_sched_barrier(0);
    __builtin_amdgcn_s_setprio(1);
#pragma unroll
    for (int mi = 0; mi < 4; ++mi)
#pragma unroll
      for (int ni = 0; ni < 4; ++ni)
        acc[mi][ni] = __builtin_amdgcn_mfma_f32_16x16x32_bf16(aF[mi], bF[ni], acc[mi][ni], 0, 0, 0);
    __builtin_amdgcn_s_setprio(0);
    __builtin_amdgcn_s_barrier();
    __builtin_amdgcn_sched_barrier(0);

    // ===== P4: k-half 1, mi 4-7 =====
#pragma unroll
    for (int mi = 0; mi < 4; ++mi) aF[mi] = A_FRAG(4 + ks, 4 + mi);
    stage_half(Wg, N_DIM, n0, t1 * 8 + 4, nB + 8192, tid, wid); // t+1 B-half1
    asm volatile("s_waitcnt vmcnt(4)" ::: "memory");           // drain t+1's A0,B0
    __builtin_amdgcn_s_barrier();
    __builtin_amdgcn_sched_barrier(0);
    __builtin_amdgcn_s_setprio(1);
#pragma unroll
    for (int mi = 0; mi < 4; ++mi)
#pragma unroll
      for (int ni = 0; ni < 4; ++ni)
        acc[4 + mi][ni] = __builtin_amdgcn_mfma_f32_16x16x32_bf16(aF[mi], bF[ni], acc[4 + mi][ni], 0, 0, 0);
    __builtin_amdgcn_s_setprio(0);
    __builtin_amdgcn_s_barrier();
    __builtin_amdgcn_sched_barrier(0);
  }
#undef A_FRAG
#undef B_FRAG

  // don't end the block with global_load_lds writes still in flight
  asm volatile("s_waitcnt vmcnt(0)" ::: "memory");

  // ---- epilogue: D col = lane&15 (from B), row = (lane>>4)*4 + reg (from A)
  const int col0 = n0 + wc * 64 + (lane & 15);
  const int row0 = m0 + wr * 128 + ((lane >> 4) << 2);
#pragma unroll
  for (int ni = 0; ni < 4; ++ni) {
    float bv = bias[col0 + ni * 16];
#pragma unroll
    for (int mi = 0; mi < 8; ++mi) {
#pragma unroll
      for (int rr = 0; rr < 4; ++rr) {
        C[(size_t)(row0 + mi * 16 + rr) * N_DIM + col0 + ni * 16] = acc[mi][ni][rr] + bv;
      }
    }
  }
}

// ---------------- fallback: fused-dequant fp32 tiled GEMM (no workspace) ----------------
__global__ __launch_bounds__(256) void gemm_fb(const float* __restrict__ A,
                                               const int* __restrict__ qweight,
                                               const int* __restrict__ qzeros,
                                               const float* __restrict__ scales,
                                               const float* __restrict__ bias,
                                               float* __restrict__ C) {
  __shared__ float as[64][17];
  __shared__ float bs2[16][65];
  int tid = threadIdx.x;
  int tx = tid & 15, ty = tid >> 4;
  int bn = blockIdx.x % (N_DIM / 64);
  int bm = blockIdx.x / (N_DIM / 64);
  int m0 = bm * 64, n0 = bn * 64;
  float acc[4][4] = {};
  for (int k0 = 0; k0 < K_DIM; k0 += 16) {
#pragma unroll
    for (int i = 0; i < 4; ++i) {
      int idx = i * 256 + tid;
      int r = idx >> 4, c = idx & 15;
      as[r][c] = A[(size_t)(m0 + r) * K_DIM + k0 + c];
    }
#pragma unroll
    for (int i = 0; i < 4; ++i) {
      int idx = i * 256 + tid;
      int r = idx >> 6, c = idx & 63;
      int k = k0 + r, n = n0 + c;
      int g = k >> 7, p = n >> 3, j = n & 7;
      int sh = ((j >> 1) << 2) | ((j & 1) << 4);
      int q = qweight[(size_t)k * PQ + p];
      int zq = qzeros[(size_t)g * PQ + p];
      bs2[r][c] = (float)(((q >> sh) & 0xF) - ((zq >> sh) & 0xF)) * scales[(size_t)g * N_DIM + n];
    }
    __syncthreads();
#pragma unroll
    for (int kk = 0; kk < 16; ++kk) {
      float av[4], bv[4];
#pragma unroll
      for (int i = 0; i < 4; ++i) av[i] = as[ty * 4 + i][kk];
#pragma unroll
      for (int i = 0; i < 4; ++i) bv[i] = bs2[kk][tx * 4 + i];
#pragma unroll
      for (int i = 0; i < 4; ++i)
#pragma unroll
        for (int j2 = 0; j2 < 4; ++j2) acc[i][j2] += av[i] * bv[j2];
    }
    __syncthreads();
  }
#pragma unroll
  for (int i = 0; i < 4; ++i)
#pragma unroll
    for (int j2 = 0; j2 < 4; ++j2)
      C[(size_t)(m0 + ty * 4 + i) * N_DIM + n0 + tx * 4 + j2] =
          acc[i][j2] + bias[n0 + tx * 4 + j2];
}

extern "C" void kernel_launch(void* const* d_in, const int* in_sizes, int n_in,
                              void* d_out, int out_size, void* d_ws, size_t ws_size,
                              hipStream_t stream) {
  const float* inputs = (const float*)d_in[0];
  const int* qweight = (const int*)d_in[1];
  const int* qzeros = (const int*)d_in[2];
  const float* scales = (const float*)d_in[3];
  const float* bias = (const float*)d_in[4];
  float* out = (float*)d_out;

  const size_t a_bytes = (size_t)M_DIM * K_DIM * 2;  // 32 MB
  const size_t w_bytes = (size_t)K_DIM * N_DIM * 2;  // 86 MB

  if (ws_size >= a_bytes + w_bytes) {
    unsigned short* a_kp = (unsigned short*)d_ws;
    unsigned short* wg = (unsigned short*)((char*)d_ws + a_bytes);
    convert_a_t<<<(K_DIM / 8) * M_DIM / 256, 256, 0, stream>>>(inputs, a_kp);
    dequant_w<<<((K_DIM / 8) * N_DIM) / 256, 256, 0, stream>>>(qweight, qzeros, scales, wg);
    (void)hipFuncSetAttribute((const void*)gemm256,
                              hipFuncAttributeMaxDynamicSharedMemorySize, 131072);
    gemm256<<<(M_DIM / BM) * (N_DIM / BN), 512, 131072, stream>>>(a_kp, wg, bias, out);
  } else {
    gemm_fb<<<(M_DIM / 64) * (N_DIM / 64), 256, 0, stream>>>(inputs, qweight, qzeros, scales,
                                                             bias, out);
  }
}

// Round 3
// 340.580 us; speedup vs baseline: 1.4526x; 1.1657x over previous
//
#include <hip/hip_runtime.h>

#define M_DIM 4096
#define K_DIM 4096
#define N_DIM 11008
#define PQ (N_DIM / 8)   // 1376 packed columns

typedef short short8 __attribute__((ext_vector_type(8)));
typedef float f32x4 __attribute__((ext_vector_type(4)));
typedef __attribute__((address_space(3))) void lds_void;
typedef const __attribute__((address_space(1))) void g_void;

__device__ __forceinline__ unsigned short f2bf(float f) {
  unsigned int u = __float_as_uint(f);
  u += 0x7FFFu + ((u >> 16) & 1u);   // round-to-nearest-even
  return (unsigned short)(u >> 16);
}

// ---- A convert + transpose: fp32 [M][K] -> bf16 K-packed Ag[K/8][M][8] ----
__global__ __launch_bounds__(256) void convert_a_t(const float* __restrict__ a,
                                                   unsigned short* __restrict__ ag) {
  int idx = blockIdx.x * 256 + threadIdx.x;   // (kb, m), m fast
  int m = idx & (M_DIM - 1);
  int kb = idx >> 12;
  const float4* src = (const float4*)(a + (size_t)m * K_DIM + kb * 8);
  float4 v0 = src[0];
  float4 v1 = src[1];
  short8 o;
  o[0] = (short)f2bf(v0.x); o[1] = (short)f2bf(v0.y);
  o[2] = (short)f2bf(v0.z); o[3] = (short)f2bf(v0.w);
  o[4] = (short)f2bf(v1.x); o[5] = (short)f2bf(v1.y);
  o[6] = (short)f2bf(v1.z); o[7] = (short)f2bf(v1.w);
  *(short8*)(ag + (size_t)idx * 8) = o;
}

// ---- Dequant: qweight [K][P] int32 -> Wg [K/8][N][8] bf16 (K-packed) ----
__global__ __launch_bounds__(256) void dequant_w(const int* __restrict__ qweight,
                                                 const int* __restrict__ qzeros,
                                                 const float* __restrict__ scales,
                                                 unsigned short* __restrict__ wg) {
  int idx = blockIdx.x * 256 + threadIdx.x;
  int n = idx % N_DIM;
  int kb = idx / N_DIM;                 // 0..511
  int g = kb >> 4;
  int p = n >> 3;
  int j = n & 7;
  int sh = ((j >> 1) << 2) | ((j & 1) << 4);   // 4*AWQ_rev[j]
  float zp = (float)((qzeros[g * PQ + p] >> sh) & 0xF);
  float sc = scales[(size_t)g * N_DIM + n];
  short8 o;
#pragma unroll
  for (int e = 0; e < 8; ++e) {
    int q = qweight[(size_t)(kb * 8 + e) * PQ + p];
    float w = ((float)((q >> sh) & 0xF) - zp) * sc;
    o[e] = (short)f2bf(w);
  }
  *(short8*)(wg + ((size_t)kb * N_DIM + n) * 8) = o;
}

// ---------------- 256x256 8-wave pipelined bf16 MFMA GEMM ----------------
#define BM 256
#define BN 256
#define BK 64
#define NT (K_DIM / BK)   // 64 K-tiles
// LDS: 2 bufs x (A 16384 + B 16384) shorts = 128 KiB
// buf layout: A [kslot 0..7][row 0..255][8] ; B at +16384 same shape.

__device__ __forceinline__ void stage_half(const unsigned short* __restrict__ g, int ld, int off0,
                                           int krow0, unsigned short* ldsbase, int tid, int wid) {
#pragma unroll
  for (int i = 0; i < 2; ++i) {
    int c = i * 512 + tid;             // chunk id within the 16KB half
    const unsigned short* src = g + ((size_t)(krow0 + (c >> 8)) * ld + off0 + (c & 255)) * 8;
    unsigned short* dst = ldsbase + (i * 512 + wid * 64) * 8;  // wave-uniform; lane adds 16B
    __builtin_amdgcn_global_load_lds((g_void*)src, (lds_void*)dst, 16, 0, 0);
  }
}

__global__ __launch_bounds__(512, 2) void gemm256(const unsigned short* __restrict__ Ag,
                                                  const unsigned short* __restrict__ Wg,
                                                  const float* __restrict__ bias,
                                                  float* __restrict__ C) {
  extern __shared__ __align__(16) unsigned short lds[];   // 65536 shorts = 128 KB
  const int tid = threadIdx.x;
  const int lane = tid & 63;
  const int wid = tid >> 6;      // 0..7
  const int wr = wid >> 2;       // 0..1  (row half: 128 rows)
  const int wc = wid & 3;        // 0..3  (col quarter: 64 cols)
  // XCD-bijective swizzle: 688 blocks, 688 % 8 == 0
  const int wg = (blockIdx.x & 7) * 86 + (blockIdx.x >> 3);
  const int m0 = (wg & 15) * BM;
  const int n0 = (wg >> 4) * BN;

  const int ks = lane >> 4;           // k-slot within half (0..3)
  const int rowA = wr * 128 + (lane & 15);
  const int colB = wc * 64 + (lane & 15);

  f32x4 acc[8][4];
#pragma unroll
  for (int i = 0; i < 8; ++i)
#pragma unroll
    for (int j = 0; j < 4; ++j) acc[i][j] = (f32x4){0.f, 0.f, 0.f, 0.f};

  // LDS frag addresses (shorts): A: buf*32768 + kb*2048 + r*8 ; B: +16384
#define A_FRAG(buf, kb, r) (*(const short8*)(lds + (buf) * 32768 + (kb) * 2048 + (r) * 8))
#define B_FRAG(buf, kb, c) (*(const short8*)(lds + (buf) * 32768 + 16384 + (kb) * 2048 + (c) * 8))

  short8 aLo[4], aHi[4], bA[4], bB[4];

  // ---- prologue: stage tile 0 fully; wait for A0,B0; read P1(0) frags
  stage_half(Ag, M_DIM, m0, 0, lds + 0, tid, wid);              // A0(0)
  stage_half(Wg, N_DIM, n0, 0, lds + 16384, tid, wid);          // B0(0)
  stage_half(Ag, M_DIM, m0, 4, lds + 8192, tid, wid);           // A1(0)
  stage_half(Wg, N_DIM, n0, 4, lds + 16384 + 8192, tid, wid);   // B1(0)
  asm volatile("s_waitcnt vmcnt(4)" ::: "memory");
  __builtin_amdgcn_s_barrier();
#pragma unroll
  for (int mi = 0; mi < 4; ++mi) aLo[mi] = A_FRAG(0, ks, rowA + mi * 16);
#pragma unroll
  for (int ni = 0; ni < 4; ++ni) bA[ni] = B_FRAG(0, ks, colB + ni * 16);

  for (int t = 0; t < NT; ++t) {
    const int bs = t & 1;
    const int nb = bs ^ 1;
    const int t1 = (t + 1 < NT) ? (t + 1) : t;     // duplicate-stage last tile (never consumed)
    unsigned short* nA = lds + nb * 32768;
    unsigned short* nB = nA + 16384;

    // ===== SEG A: MFMA P1 (aLo x bA) ; prefetch-read aHi (P2) ; stage A0B0(t+1)
    stage_half(Ag, M_DIM, m0, t1 * 8, nA, tid, wid);
    stage_half(Wg, N_DIM, n0, t1 * 8, nB, tid, wid);
#pragma unroll
    for (int mi = 0; mi < 4; ++mi) aHi[mi] = A_FRAG(bs, ks, rowA + 64 + mi * 16);
#pragma unroll
    for (int mi = 0; mi < 4; ++mi)
#pragma unroll
      for (int ni = 0; ni < 4; ++ni)
        acc[mi][ni] = __builtin_amdgcn_mfma_f32_16x16x32_bf16(aLo[mi], bA[ni], acc[mi][ni], 0, 0, 0);
    asm volatile("s_waitcnt vmcnt(4)" ::: "memory");   // A1B1(t) landed (staged in SEG B(t-1))
    __builtin_amdgcn_s_barrier();

    // ===== SEG B: MFMA P2 (aHi x bA) ; read aLo',bB (P3) ; stage A1B1(t+1) ;
    //              read aHi' (P4) ; MFMA P3 (aLo' x bB)
#pragma unroll
    for (int mi = 0; mi < 4; ++mi) aLo[mi] = A_FRAG(bs, 4 + ks, rowA + mi * 16);
#pragma unroll
    for (int ni = 0; ni < 4; ++ni) bB[ni] = B_FRAG(bs, 4 + ks, colB + ni * 16);
#pragma unroll
    for (int mi = 0; mi < 4; ++mi)
#pragma unroll
      for (int ni = 0; ni < 4; ++ni)
        acc[4 + mi][ni] = __builtin_amdgcn_mfma_f32_16x16x32_bf16(aHi[mi], bA[ni], acc[4 + mi][ni], 0, 0, 0);
    stage_half(Ag, M_DIM, m0, t1 * 8 + 4, nA + 8192, tid, wid);
    stage_half(Wg, N_DIM, n0, t1 * 8 + 4, nB + 8192, tid, wid);
#pragma unroll
    for (int mi = 0; mi < 4; ++mi) aHi[mi] = A_FRAG(bs, 4 + ks, rowA + 64 + mi * 16);
#pragma unroll
    for (int mi = 0; mi < 4; ++mi)
#pragma unroll
      for (int ni = 0; ni < 4; ++ni)
        acc[mi][ni] = __builtin_amdgcn_mfma_f32_16x16x32_bf16(aLo[mi], bB[ni], acc[mi][ni], 0, 0, 0);
    asm volatile("s_waitcnt vmcnt(4)" ::: "memory");   // A0B0(t+1) landed
    __builtin_amdgcn_s_barrier();

    // ===== SEG C: read aLo,bA for P1(t+1) from nb ; MFMA P4 (aHi x bB)
#pragma unroll
    for (int mi = 0; mi < 4; ++mi) aLo[mi] = A_FRAG(nb, ks, rowA + mi * 16);
#pragma unroll
    for (int ni = 0; ni < 4; ++ni) bA[ni] = B_FRAG(nb, ks, colB + ni * 16);
#pragma unroll
    for (int mi = 0; mi < 4; ++mi)
#pragma unroll
      for (int ni = 0; ni < 4; ++ni)
        acc[4 + mi][ni] = __builtin_amdgcn_mfma_f32_16x16x32_bf16(aHi[mi], bB[ni], acc[4 + mi][ni], 0, 0, 0);
  }
#undef A_FRAG
#undef B_FRAG

  asm volatile("s_waitcnt vmcnt(0)" ::: "memory");  // no in-flight LDS writes at exit

  // ---- epilogue: D col = lane&15, row = (lane>>4)*4 + reg; nontemporal C stores
  const int col0 = n0 + wc * 64 + (lane & 15);
  const int row0 = m0 + wr * 128 + ((lane >> 4) << 2);
#pragma unroll
  for (int ni = 0; ni < 4; ++ni) {
    float bv = bias[col0 + ni * 16];
#pragma unroll
    for (int mi = 0; mi < 8; ++mi) {
#pragma unroll
      for (int rr = 0; rr < 4; ++rr) {
        __builtin_nontemporal_store(acc[mi][ni][rr] + bv,
            &C[(size_t)(row0 + mi * 16 + rr) * N_DIM + col0 + ni * 16]);
      }
    }
  }
}

// ---------------- fallback: fused-dequant fp32 tiled GEMM (no workspace) ----------------
__global__ __launch_bounds__(256) void gemm_fb(const float* __restrict__ A,
                                               const int* __restrict__ qweight,
                                               const int* __restrict__ qzeros,
                                               const float* __restrict__ scales,
                                               const float* __restrict__ bias,
                                               float* __restrict__ C) {
  __shared__ float as[64][17];
  __shared__ float bs2[16][65];
  int tid = threadIdx.x;
  int tx = tid & 15, ty = tid >> 4;
  int bn = blockIdx.x % (N_DIM / 64);
  int bm = blockIdx.x / (N_DIM / 64);
  int m0 = bm * 64, n0 = bn * 64;
  float acc[4][4] = {};
  for (int k0 = 0; k0 < K_DIM; k0 += 16) {
#pragma unroll
    for (int i = 0; i < 4; ++i) {
      int idx = i * 256 + tid;
      int r = idx >> 4, c = idx & 15;
      as[r][c] = A[(size_t)(m0 + r) * K_DIM + k0 + c];
    }
#pragma unroll
    for (int i = 0; i < 4; ++i) {
      int idx = i * 256 + tid;
      int r = idx >> 6, c = idx & 63;
      int k = k0 + r, n = n0 + c;
      int g = k >> 7, p = n >> 3, j = n & 7;
      int sh = ((j >> 1) << 2) | ((j & 1) << 4);
      int q = qweight[(size_t)k * PQ + p];
      int zq = qzeros[(size_t)g * PQ + p];
      bs2[r][c] = (float)(((q >> sh) & 0xF) - ((zq >> sh) & 0xF)) * scales[(size_t)g * N_DIM + n];
    }
    __syncthreads();
#pragma unroll
    for (int kk = 0; kk < 16; ++kk) {
      float av[4], bv[4];
#pragma unroll
      for (int i = 0; i < 4; ++i) av[i] = as[ty * 4 + i][kk];
#pragma unroll
      for (int i = 0; i < 4; ++i) bv[i] = bs2[kk][tx * 4 + i];
#pragma unroll
      for (int i = 0; i < 4; ++i)
#pragma unroll
        for (int j2 = 0; j2 < 4; ++j2) acc[i][j2] += av[i] * bv[j2];
    }
    __syncthreads();
  }
#pragma unroll
  for (int i = 0; i < 4; ++i)
#pragma unroll
    for (int j2 = 0; j2 < 4; ++j2)
      C[(size_t)(m0 + ty * 4 + i) * N_DIM + n0 + tx * 4 + j2] =
          acc[i][j2] + bias[n0 + tx * 4 + j2];
}

extern "C" void kernel_launch(void* const* d_in, const int* in_sizes, int n_in,
                              void* d_out, int out_size, void* d_ws, size_t ws_size,
                              hipStream_t stream) {
  const float* inputs = (const float*)d_in[0];
  const int* qweight = (const int*)d_in[1];
  const int* qzeros = (const int*)d_in[2];
  const float* scales = (const float*)d_in[3];
  const float* bias = (const float*)d_in[4];
  float* out = (float*)d_out;

  const size_t a_bytes = (size_t)M_DIM * K_DIM * 2;  // 32 MB
  const size_t w_bytes = (size_t)K_DIM * N_DIM * 2;  // 86 MB

  if (ws_size >= a_bytes + w_bytes) {
    unsigned short* a_kp = (unsigned short*)d_ws;
    unsigned short* wg = (unsigned short*)((char*)d_ws + a_bytes);
    convert_a_t<<<(K_DIM / 8) * M_DIM / 256, 256, 0, stream>>>(inputs, a_kp);
    dequant_w<<<((K_DIM / 8) * N_DIM) / 256, 256, 0, stream>>>(qweight, qzeros, scales, wg);
    (void)hipFuncSetAttribute((const void*)gemm256,
                              hipFuncAttributeMaxDynamicSharedMemorySize, 131072);
    gemm256<<<(M_DIM / BM) * (N_DIM / BN), 512, 131072, stream>>>(a_kp, wg, bias, out);
  } else {
    gemm_fb<<<(M_DIM / 64) * (N_DIM / 64), 256, 0, stream>>>(inputs, qweight, qzeros, scales,
                                                             bias, out);
  }
}